// Round 1
// baseline (10505.090 us; speedup 1.0000x reference)
//
#include <hip/hip_runtime.h>

// ---- problem dims (fixed) ----
#define NCLS 4
#define BS   16
#define HH   64
#define WW   64
#define OC   12
#define NT   32
#define HW   4096            // HH*WW
#define PIX  65536           // BS*HW
#define STATE 786432         // PIX*OC   (one class slot / gen state)
#define BANK  3145728        // NCLS*STATE

// jax.nn.hard_sigmoid = relu6(x+3)/6
__device__ __forceinline__ float hsig(float v){
    return fminf(fmaxf((v + 3.0f) * (1.0f/6.0f), 0.0f), 1.0f);
}

// acc[gate][j] += v * W[co] for co = gate*12 + (c0+j); w points at row + c0
__device__ __forceinline__ void fma16(float v, const float* __restrict__ w, float acc[4][4]){
    #pragma unroll
    for (int g = 0; g < 4; ++g){
        #pragma unroll
        for (int j = 0; j < 4; ++j)
            acc[g][j] = fmaf(v, w[g*12 + j], acc[g][j]);
    }
}

// 4 consecutive input channels (float4) against 4 consecutive weight rows (stride 48)
__device__ __forceinline__ void fma_f4(float4 v, const float* __restrict__ w, float acc[4][4]){
    fma16(v.x, w,       acc);
    fma16(v.y, w + 48,  acc);
    fma16(v.z, w + 96,  acc);
    fma16(v.w, w + 144, acc);
}

__device__ __forceinline__ void lstm_epilogue(float acc[4][4], const float* __restrict__ bias,
                                              int c0, float* __restrict__ cptr,
                                              float* __restrict__ hptr)
{
    float4 cold4 = *(const float4*)cptr;
    float cold[4] = {cold4.x, cold4.y, cold4.z, cold4.w};
    float cn[4], hn[4];
    #pragma unroll
    for (int j = 0; j < 4; ++j){
        float zi = acc[0][j] + bias[c0 + j];
        float zf = acc[1][j] + bias[12 + c0 + j];
        float zg = acc[2][j] + bias[24 + c0 + j];
        float zo = acc[3][j] + bias[36 + c0 + j];
        float c2 = hsig(zf) * cold[j] + hsig(zi) * tanhf(zg);
        cn[j] = c2;
        hn[j] = hsig(zo) * tanhf(c2);
    }
    *(float4*)cptr = make_float4(cn[0], cn[1], cn[2], cn[3]);
    *(float4*)hptr = make_float4(hn[0], hn[1], hn[2], hn[3]);
}

// ---------------- general cell ----------------
// x_gen = class_h bank viewed as (BS,HH,WW,48); recurrent input gen_h (12 ch).
// grid: 768 blocks x 256. wave -> (q, row); thread handles 1 pixel, channels [4q,4q+4).
__global__ __launch_bounds__(256) void gen_kernel(
    const float* __restrict__ xgen_,   // BANK floats, viewed (16,64,64,48)
    const float* __restrict__ hin_,    // STATE
    float* __restrict__ hout,
    float* __restrict__ cstate,        // STATE, in-place
    const float* __restrict__ Wx_,     // (3,3,48,48)
    const float* __restrict__ Wh_,     // (3,3,12,48)
    const float* __restrict__ bias_)   // (48)
{
    const float* xgen = (const float*)__builtin_assume_aligned(xgen_, 16);
    const float* hin  = (const float*)__builtin_assume_aligned(hin_, 16);
    const float* Wx   = (const float*)__builtin_assume_aligned(Wx_, 16);
    const float* Wh   = (const float*)__builtin_assume_aligned(Wh_, 16);
    const float* bias = (const float*)__builtin_assume_aligned(bias_, 16);

    int gw   = blockIdx.x * 4 + (threadIdx.x >> 6);   // global wave id [0,3072)
    int lane = threadIdx.x & 63;
    int q    = gw >> 10;          // channel-third, uniform per wave
    int pw   = gw & 1023;         // pixel-row id (b*64 + y)
    int p    = pw * 64 + lane;    // pixel
    int b    = p >> 12;
    int y    = (p >> 6) & 63;
    int x    = p & 63;
    int c0   = q * 4;

    float acc[4][4];
    #pragma unroll
    for (int g = 0; g < 4; ++g)
        #pragma unroll
        for (int j = 0; j < 4; ++j) acc[g][j] = 0.0f;

    for (int ky = 0; ky < 3; ++ky){
        int yy = y + ky - 1;
        if (yy < 0 || yy >= HH) continue;
        for (int kx = 0; kx < 3; ++kx){
            int xx = x + kx - 1;
            if (xx < 0 || xx >= WW) continue;
            int pin = (b << 12) + (yy << 6) + xx;
            const float* xp = xgen + pin * 48;
            const float* hp = hin  + pin * 12;
            const float* wx = Wx + (ky*3 + kx) * 48 * 48 + c0;
            const float* wh = Wh + (ky*3 + kx) * 12 * 48 + c0;
            for (int ci = 0; ci < 48; ci += 4){
                float4 v = *(const float4*)(xp + ci);
                fma_f4(v, wx + ci*48, acc);
            }
            for (int ci = 0; ci < 12; ci += 4){
                float4 v = *(const float4*)(hp + ci);
                fma_f4(v, wh + ci*48, acc);
            }
        }
    }
    lstm_epilogue(acc, bias, c0, cstate + p*12 + c0, hout + p*12 + c0);
}

// ---------------- class cell ----------------
// aug = concat(frame(12), gen_h_new(12)); recurrent = class_h[cid] (12 ch).
// c-state for slot cid updated in place; h_new -> htmp (scattered by next kernel).
__global__ __launch_bounds__(256) void class_kernel(
    const float* __restrict__ xall_,     // (BS,NT,HH,WW,OC)
    const int*   __restrict__ ids,
    int t,
    const float* __restrict__ ghn_,      // STATE (fresh gen_h)
    const float* __restrict__ class_h_,  // BANK
    float* __restrict__ class_c,         // BANK, slot cid in-place
    const float* __restrict__ Wx_,       // (3,3,24,48)
    const float* __restrict__ Wh_,       // (3,3,12,48)
    const float* __restrict__ bias_,     // (48)
    float* __restrict__ htmp)
{
    const float* xall    = (const float*)__builtin_assume_aligned(xall_, 16);
    const float* ghn     = (const float*)__builtin_assume_aligned(ghn_, 16);
    const float* class_h = (const float*)__builtin_assume_aligned(class_h_, 16);
    const float* Wx      = (const float*)__builtin_assume_aligned(Wx_, 16);
    const float* Wh      = (const float*)__builtin_assume_aligned(Wh_, 16);
    const float* bias    = (const float*)__builtin_assume_aligned(bias_, 16);

    int gw   = blockIdx.x * 4 + (threadIdx.x >> 6);
    int lane = threadIdx.x & 63;
    int q    = gw >> 10;
    int pw   = gw & 1023;
    int p    = pw * 64 + lane;
    int b    = p >> 12;
    int y    = (p >> 6) & 63;
    int x    = p & 63;
    int c0   = q * 4;

    int cid = ids[t];
    const float* hs = class_h + (size_t)cid * STATE;          // recurrent h (slot cid)
    float*       cc = class_c + (size_t)cid * STATE;          // c state (slot cid)
    const float* frame = xall + (size_t)(b * NT + t) * HW * OC;

    float acc[4][4];
    #pragma unroll
    for (int g = 0; g < 4; ++g)
        #pragma unroll
        for (int j = 0; j < 4; ++j) acc[g][j] = 0.0f;

    for (int ky = 0; ky < 3; ++ky){
        int yy = y + ky - 1;
        if (yy < 0 || yy >= HH) continue;
        for (int kx = 0; kx < 3; ++kx){
            int xx = x + kx - 1;
            if (xx < 0 || xx >= WW) continue;
            int pl  = (yy << 6) + xx;          // in-image pixel
            int pin = (b << 12) + pl;          // global pixel
            const float* fp = frame + pl  * 12;
            const float* gp = ghn   + pin * 12;
            const float* hp = hs    + pin * 12;
            const float* wx = Wx + (ky*3 + kx) * 24 * 48 + c0;
            const float* wh = Wh + (ky*3 + kx) * 12 * 48 + c0;
            for (int ci = 0; ci < 12; ci += 4){
                float4 v = *(const float4*)(fp + ci);
                fma_f4(v, wx + ci*48, acc);
            }
            for (int ci = 0; ci < 12; ci += 4){
                float4 v = *(const float4*)(gp + ci);
                fma_f4(v, wx + (12 + ci)*48, acc);
            }
            for (int ci = 0; ci < 12; ci += 4){
                float4 v = *(const float4*)(hp + ci);
                fma_f4(v, wh + ci*48, acc);
            }
        }
    }
    lstm_epilogue(acc, bias, c0, cc + p*12 + c0, htmp + p*12 + c0);
}

// scatter h_new into class_h[cid] and accumulate the time-sum output
__global__ __launch_bounds__(256) void scatter_kernel(
    const int* __restrict__ ids, int t,
    const float* __restrict__ htmp,
    float* __restrict__ class_h,
    float* __restrict__ out)
{
    int i = blockIdx.x * blockDim.x + threadIdx.x;   // float4 index, < STATE/4
    int cid = ids[t];
    float4 v = ((const float4*)htmp)[i];
    ((float4*)(class_h + (size_t)cid * STATE))[i] = v;
    float4* o = (float4*)out;
    float4 ov = o[i];
    ov.x += v.x; ov.y += v.y; ov.z += v.z; ov.w += v.w;
    o[i] = ov;
}

extern "C" void kernel_launch(void* const* d_in, const int* in_sizes, int n_in,
                              void* d_out, int out_size, void* d_ws, size_t ws_size,
                              hipStream_t stream)
{
    (void)in_sizes; (void)n_in; (void)out_size; (void)ws_size;
    const float* x    = (const float*)d_in[0];
    const int*   ids  = (const int*)  d_in[1];
    const float* Wxg  = (const float*)d_in[2];
    const float* Whg  = (const float*)d_in[3];
    const float* bg   = (const float*)d_in[4];
    const float* Wxc  = (const float*)d_in[5];
    const float* Whc  = (const float*)d_in[6];
    const float* bc   = (const float*)d_in[7];
    float* out = (float*)d_out;

    float* ws      = (float*)d_ws;
    float* class_h = ws;                    // BANK
    float* class_c = class_h + BANK;        // BANK
    float* gen_h0  = class_c + BANK;        // STATE
    float* gen_h1  = gen_h0 + STATE;        // STATE
    float* gen_c   = gen_h1 + STATE;        // STATE
    float* h_tmp   = gen_c  + STATE;        // STATE
    // total: 2*BANK + 4*STATE = 9,437,184 floats = 36 MiB

    hipMemsetAsync(class_h, 0, (size_t)BANK  * sizeof(float), stream);
    hipMemsetAsync(class_c, 0, (size_t)BANK  * sizeof(float), stream);
    hipMemsetAsync(gen_h0,  0, (size_t)STATE * sizeof(float), stream);
    hipMemsetAsync(gen_c,   0, (size_t)STATE * sizeof(float), stream);
    hipMemsetAsync(out,     0, (size_t)STATE * sizeof(float), stream);

    for (int t = 0; t < NT; ++t){
        float* hin  = (t & 1) ? gen_h1 : gen_h0;
        float* hnew = (t & 1) ? gen_h0 : gen_h1;
        gen_kernel<<<768, 256, 0, stream>>>(class_h, hin, hnew, gen_c, Wxg, Whg, bg);
        class_kernel<<<768, 256, 0, stream>>>(x, ids, t, hnew, class_h, class_c,
                                              Wxc, Whc, bc, h_tmp);
        scatter_kernel<<<768, 256, 0, stream>>>(ids, t, h_tmp, class_h, out);
    }
}

// Round 2
// 1487.849 us; speedup vs baseline: 7.0606x; 7.0606x over previous
//
#include <hip/hip_runtime.h>
#include <hip/hip_bf16.h>

// ---- problem dims (fixed) ----
#define NCLS 4
#define BS   16
#define NT   32
#define OC   12
#define HW   4096
#define PIX  65536
#define STATE 786432        // PIX*OC
#define BANK  3145728       // NCLS*STATE

typedef short bf16x8 __attribute__((ext_vector_type(8)));
typedef float f32x4  __attribute__((ext_vector_type(4)));

// jax.nn.hard_sigmoid = relu6(x+3)/6
__device__ __forceinline__ float hsig(float v){
    return fminf(fmaxf((v + 3.0f) * (1.0f/6.0f), 0.0f), 1.0f);
}
__device__ __forceinline__ short f2bf(float f){
    union { __hip_bfloat16 h; short s; } u;
    u.h = __float2bfloat16(f);   // RNE
    return u.s;
}

// =====================================================================
// Weight repack: fragment-order bf16 weights.
// wgt[cell][tap][kb][nt][lane] = bf16x8 with element j = B[k][n],
//   k = kb*32 + (lane>>4)*8 + j, n = nt*16 + (lane&15)
// gen : k<48 -> Wxg[tap][k][n]; k<60 -> Whg[tap][k-48][n]; else 0
// cls : k<24 -> Wxc[tap][k][n]; k<36 -> Whc[tap][k-24][n]; else 0
// =====================================================================
__global__ __launch_bounds__(256) void repack_kernel(
    const float* __restrict__ Wxg, const float* __restrict__ Whg,
    const float* __restrict__ Wxc, const float* __restrict__ Whc,
    bf16x8* __restrict__ wgt)
{
    int id = blockIdx.x * 256 + threadIdx.x;    // < 6912
    if (id >= 6912) return;
    int cell = id / 3456;
    int rem  = id - cell * 3456;
    int tap  = rem / 384;  rem -= tap * 384;
    int kb   = rem / 192;  rem -= kb * 192;
    int nt   = rem / 64;
    int lane = rem - nt * 64;
    int quad = lane >> 4;
    int n    = nt * 16 + (lane & 15);
    union { bf16x8 v; short s[8]; } o;
    #pragma unroll
    for (int j = 0; j < 8; ++j){
        int k = kb * 32 + quad * 8 + j;
        float f = 0.0f;
        if (cell == 0){
            if (k < 48)      f = Wxg[(tap*48 + k)*48 + n];
            else if (k < 60) f = Whg[(tap*12 + (k-48))*48 + n];
        } else {
            if (k < 24)      f = Wxc[(tap*24 + k)*48 + n];
            else if (k < 36) f = Whc[(tap*12 + (k-24))*48 + n];
        }
        o.s[j] = f2bf(f);
    }
    wgt[id] = o.v;
}

// =====================================================================
// LDS halo layout (both cells): plane-major  halo[q8][r][c][8ch] bf16,
//   q8 = k/8 in [0,8), r in [0,3), c in [0,66)  (x' = c-1)
// A ds_read_b128 then has 16B m-stride -> conflict-free per quarter-wave.
// =====================================================================
#define HALO_SHORTS (8*198*8)     // 12672 shorts = 25344 B

// ---------------- general cell ----------------
// x = class_h bank raw-viewed as (16,64,64,48) + recurrent gen_h (12ch).
// block = 64 pixels (one row of one image), 4 waves; wave w -> pixels
// [16w,16w+16), all 48 outch (3 N-tiles).
__global__ __launch_bounds__(256) void gen_kernel(
    const short* __restrict__ bank,    // (PIX,48) bf16  (class_h_bf flat view)
    const short* __restrict__ hin,     // (PIX,12) bf16
    short* __restrict__ hout,          // (PIX,12) bf16
    float* __restrict__ cstate,        // (PIX,12) f32, in-place
    const bf16x8* __restrict__ wgt,    // 3456 frags
    const float* __restrict__ bias)    // (48) f32
{
    __shared__ __align__(16) short halo[HALO_SHORTS];
    const int tid = threadIdx.x;
    const int p0  = blockIdx.x << 6;
    const int b   = p0 >> 12;
    const int y   = (p0 >> 6) & 63;

    // ---- stage halo: tasks = (rc, q8), 1584 chunks of 8 ch ----
    for (int t = tid; t < 1584; t += 256){
        int rc = t >> 3, q8 = t & 7;
        int r  = rc / 66, c = rc - r * 66;
        int yy = y + r - 1, xx = c - 1;
        bool valid = (yy >= 0) & (yy < 64) & (xx >= 0) & (xx < 64);
        int p = (b << 12) + (yy << 6) + xx;
        union { bf16x8 v; uint2 u2[2]; uint4 u4; } ch;
        ch.u4 = make_uint4(0u, 0u, 0u, 0u);
        if (valid){
            if (q8 < 6){                       // bank ch 8*q8 .. 8*q8+7
                ch.u4 = *(const uint4*)(bank + p*48 + q8*8);
            } else if (q8 == 6){               // gen_h ch 0..7
                ch.u2[0] = *(const uint2*)(hin + p*12);
                ch.u2[1] = *(const uint2*)(hin + p*12 + 4);
            } else {                           // gen_h ch 8..11 + pad
                ch.u2[0] = *(const uint2*)(hin + p*12 + 8);
            }
        }
        *(bf16x8*)&halo[(q8*198 + rc)*8] = ch.v;
    }
    __syncthreads();

    const int lane = tid & 63;
    const int w    = tid >> 6;
    const int m    = lane & 15;
    const int quad = lane >> 4;
    const int colbase = 16*w + m;      // halo col index = colbase + kx

    f32x4 acc0 = {0.f,0.f,0.f,0.f};
    f32x4 acc1 = acc0, acc2 = acc0;
    #pragma unroll
    for (int ky = 0; ky < 3; ++ky){
        #pragma unroll
        for (int kx = 0; kx < 3; ++kx){
            const int tap = ky*3 + kx;
            #pragma unroll
            for (int kb = 0; kb < 2; ++kb){
                const bf16x8 a = *(const bf16x8*)
                    &halo[(((kb*4 + quad)*198) + ky*66 + colbase + kx)*8];
                const bf16x8* wp = wgt + ((tap*2 + kb)*3)*64 + lane;
                acc0 = __builtin_amdgcn_mfma_f32_16x16x32_bf16(a, wp[0],   acc0, 0,0,0);
                acc1 = __builtin_amdgcn_mfma_f32_16x16x32_bf16(a, wp[64],  acc1, 0,0,0);
                acc2 = __builtin_amdgcn_mfma_f32_16x16x32_bf16(a, wp[128], acc2, 0,0,0);
            }
        }
    }

    // ---- epilogue: transpose z through LDS (reuse halo), LSTM math ----
    __syncthreads();                       // all waves done reading halo
    float* zw = ((float*)halo) + w * 768;  // 16 px x 48 ch per wave
    #pragma unroll
    for (int r = 0; r < 4; ++r){
        zw[(quad*4 + r)*48 +      m] = acc0[r];
        zw[(quad*4 + r)*48 + 16 + m] = acc1[r];
        zw[(quad*4 + r)*48 + 32 + m] = acc2[r];
    }
    __syncthreads();
    const int pbase = p0 + 16*w;
    #pragma unroll
    for (int s = 0; s < 3; ++s){
        int idx = lane*3 + s;              // 0..191
        int px  = idx / 12;
        int j   = idx - px*12;
        float zi = zw[px*48 +      j] + bias[j];
        float zf = zw[px*48 + 12 + j] + bias[12 + j];
        float zg = zw[px*48 + 24 + j] + bias[24 + j];
        float zo = zw[px*48 + 36 + j] + bias[36 + j];
        int off = pbase*12 + idx;
        float cold = cstate[off];
        float cn = hsig(zf)*cold + hsig(zi)*tanhf(zg);
        cstate[off] = cn;
        hout[off] = f2bf(hsig(zo)*tanhf(cn));
    }
}

// ---------------- class cell ----------------
// aug = concat(frame(12), gen_h(12)) + recurrent class_h[cid](12).
// k: 0..11 frame, 12..23 gen_h, 24..35 class_h, 36..63 zero.
__global__ __launch_bounds__(256) void class_kernel(
    const float* __restrict__ xall,    // (BS,NT,64,64,12) f32
    const int*   __restrict__ ids, int t,
    const short* __restrict__ ghn,     // (PIX,12) bf16 (fresh gen_h)
    const short* __restrict__ chbank,  // (NCLS,PIX,12) bf16
    float* __restrict__ class_c,       // (NCLS,PIX,12) f32
    const bf16x8* __restrict__ wgt,    // class frags
    const float* __restrict__ bias,
    short* __restrict__ htmp,          // (PIX,12) bf16
    float* __restrict__ out)           // (PIX,12) f32, accumulated
{
    __shared__ __align__(16) short halo[HALO_SHORTS];
    const int tid = threadIdx.x;
    const int p0  = blockIdx.x << 6;
    const int b   = p0 >> 12;
    const int y   = (p0 >> 6) & 63;
    const int cid = ids[t];
    const short* chs   = chbank + (size_t)cid * STATE;
    const float* frame = xall + (size_t)(b*NT + t) * (HW*12);

    for (int tk = tid; tk < 1584; tk += 256){
        int rc = tk >> 3, q8 = tk & 7;
        int r  = rc / 66, c = rc - r * 66;
        int yy = y + r - 1, xx = c - 1;
        bool valid = (yy >= 0) & (yy < 64) & (xx >= 0) & (xx < 64);
        int pl = (yy << 6) + xx;
        int p  = (b << 12) + pl;
        union { bf16x8 v; uint2 u2[2]; uint4 u4; short s[8]; } ch;
        ch.u4 = make_uint4(0u, 0u, 0u, 0u);
        if (valid){
            if (q8 == 0){                      // frame ch 0..7
                float4 f0 = *(const float4*)(frame + pl*12);
                float4 f1 = *(const float4*)(frame + pl*12 + 4);
                ch.s[0]=f2bf(f0.x); ch.s[1]=f2bf(f0.y); ch.s[2]=f2bf(f0.z); ch.s[3]=f2bf(f0.w);
                ch.s[4]=f2bf(f1.x); ch.s[5]=f2bf(f1.y); ch.s[6]=f2bf(f1.z); ch.s[7]=f2bf(f1.w);
            } else if (q8 == 1){               // frame 8..11 | gen_h 0..3
                float4 f2 = *(const float4*)(frame + pl*12 + 8);
                ch.s[0]=f2bf(f2.x); ch.s[1]=f2bf(f2.y); ch.s[2]=f2bf(f2.z); ch.s[3]=f2bf(f2.w);
                ch.u2[1] = *(const uint2*)(ghn + p*12);
            } else if (q8 == 2){               // gen_h 4..11
                ch.u2[0] = *(const uint2*)(ghn + p*12 + 4);
                ch.u2[1] = *(const uint2*)(ghn + p*12 + 8);
            } else if (q8 == 3){               // class_h 0..7
                ch.u2[0] = *(const uint2*)(chs + p*12);
                ch.u2[1] = *(const uint2*)(chs + p*12 + 4);
            } else if (q8 == 4){               // class_h 8..11 + pad
                ch.u2[0] = *(const uint2*)(chs + p*12 + 8);
            }
            // q8 5..7: zeros
        }
        *(bf16x8*)&halo[(q8*198 + rc)*8] = ch.v;
    }
    __syncthreads();

    const int lane = tid & 63;
    const int w    = tid >> 6;
    const int m    = lane & 15;
    const int quad = lane >> 4;
    const int colbase = 16*w + m;

    f32x4 acc0 = {0.f,0.f,0.f,0.f};
    f32x4 acc1 = acc0, acc2 = acc0;
    #pragma unroll
    for (int ky = 0; ky < 3; ++ky){
        #pragma unroll
        for (int kx = 0; kx < 3; ++kx){
            const int tap = ky*3 + kx;
            #pragma unroll
            for (int kb = 0; kb < 2; ++kb){
                const bf16x8 a = *(const bf16x8*)
                    &halo[(((kb*4 + quad)*198) + ky*66 + colbase + kx)*8];
                const bf16x8* wp = wgt + ((tap*2 + kb)*3)*64 + lane;
                acc0 = __builtin_amdgcn_mfma_f32_16x16x32_bf16(a, wp[0],   acc0, 0,0,0);
                acc1 = __builtin_amdgcn_mfma_f32_16x16x32_bf16(a, wp[64],  acc1, 0,0,0);
                acc2 = __builtin_amdgcn_mfma_f32_16x16x32_bf16(a, wp[128], acc2, 0,0,0);
            }
        }
    }

    __syncthreads();
    float* zw = ((float*)halo) + w * 768;
    #pragma unroll
    for (int r = 0; r < 4; ++r){
        zw[(quad*4 + r)*48 +      m] = acc0[r];
        zw[(quad*4 + r)*48 + 16 + m] = acc1[r];
        zw[(quad*4 + r)*48 + 32 + m] = acc2[r];
    }
    __syncthreads();
    float* cc = class_c + (size_t)cid * STATE;
    const int pbase = p0 + 16*w;
    #pragma unroll
    for (int s = 0; s < 3; ++s){
        int idx = lane*3 + s;
        int px  = idx / 12;
        int j   = idx - px*12;
        float zi = zw[px*48 +      j] + bias[j];
        float zf = zw[px*48 + 12 + j] + bias[12 + j];
        float zg = zw[px*48 + 24 + j] + bias[24 + j];
        float zo = zw[px*48 + 36 + j] + bias[36 + j];
        int off = pbase*12 + idx;
        float cold = cc[off];
        float cn = hsig(zf)*cold + hsig(zi)*tanhf(zg);
        cc[off] = cn;
        float h = hsig(zo)*tanhf(cn);
        htmp[off] = f2bf(h);
        out[off] += h;              // time-sum in fp32 (pre-rounding h)
    }
}

// scatter h_new (bf16) into class_h_bf[cid]
__global__ __launch_bounds__(256) void scatter_kernel(
    const int* __restrict__ ids, int t,
    const short* __restrict__ htmp, short* __restrict__ chbank)
{
    int i = blockIdx.x * 256 + threadIdx.x;   // < STATE/8 = 98304
    int cid = ids[t];
    ((uint4*)(chbank + (size_t)cid * STATE))[i] = ((const uint4*)htmp)[i];
}

extern "C" void kernel_launch(void* const* d_in, const int* in_sizes, int n_in,
                              void* d_out, int out_size, void* d_ws, size_t ws_size,
                              hipStream_t stream)
{
    (void)in_sizes; (void)n_in; (void)out_size; (void)ws_size;
    const float* x    = (const float*)d_in[0];
    const int*   ids  = (const int*)  d_in[1];
    const float* Wxg  = (const float*)d_in[2];
    const float* Whg  = (const float*)d_in[3];
    const float* bg   = (const float*)d_in[4];
    const float* Wxc  = (const float*)d_in[5];
    const float* Whc  = (const float*)d_in[6];
    const float* bc   = (const float*)d_in[7];
    float* out = (float*)d_out;

    char* base = (char*)d_ws;
    short*  class_h_bf = (short*) (base);               // 2*BANK  = 6,291,456 B
    float*  class_c    = (float*) (base + 6291456);     // 4*BANK  = 12,582,912
    short*  gen_h0     = (short*) (base + 18874368);    // 2*STATE = 1,572,864
    short*  gen_h1     = (short*) (base + 20447232);    // 2*STATE
    float*  gen_c      = (float*) (base + 22020096);    // 4*STATE = 3,145,728
    short*  h_tmp      = (short*) (base + 25165824);    // 2*STATE
    bf16x8* wgt        = (bf16x8*)(base + 26738688);    // 6912*16 = 110,592
    bf16x8* wgt_cls    = wgt + 3456;

    hipMemsetAsync(class_h_bf, 0, (size_t)2*BANK,  stream);
    hipMemsetAsync(class_c,    0, (size_t)4*BANK,  stream);
    hipMemsetAsync(gen_h0,     0, (size_t)2*STATE, stream);
    hipMemsetAsync(gen_c,      0, (size_t)4*STATE, stream);
    hipMemsetAsync(out,        0, (size_t)4*STATE, stream);

    repack_kernel<<<27, 256, 0, stream>>>(Wxg, Whg, Wxc, Whc, wgt);

    for (int t = 0; t < NT; ++t){
        short* hin  = (t & 1) ? gen_h1 : gen_h0;
        short* hnew = (t & 1) ? gen_h0 : gen_h1;
        gen_kernel<<<1024, 256, 0, stream>>>(class_h_bf, hin, hnew, gen_c, wgt, bg);
        class_kernel<<<1024, 256, 0, stream>>>(x, ids, t, hnew, class_h_bf, class_c,
                                               wgt_cls, bc, h_tmp, out);
        scatter_kernel<<<384, 256, 0, stream>>>(ids, t, h_tmp, class_h_bf);
    }
}